// Round 6
// baseline (694.464 us; speedup 1.0000x reference)
//
#include <hip/hip_runtime.h>

typedef unsigned short u16;
typedef unsigned int   u32;
typedef __attribute__((ext_vector_type(8))) _Float16 f16x8;
typedef __attribute__((ext_vector_type(4))) float f32x4;

constexpr int B_  = 4;
constexpr int C0  = 128;
constexpr int C1  = 32;
constexpr int H_  = 96;
constexpr int W_  = 96;
constexpr int HW  = H_ * W_;        // 9216
constexpr int PT  = 64;
constexpr int TPB = HW / PT;        // 144
constexpr int NTILE = B_ * TPB;     // 576

__device__ inline u16 f2h(float f) {
    _Float16 h = (_Float16)f;
    return __builtin_bit_cast(u16, h);
}

// ---------------------------------------------------------------------------
// Weight prep:
//  wofft[c][o*9+t]   f32 <- w_off[o][c][t]     (conv_off, round-1 proven)
//  wdNt[k][c][o]     f32 <- w_d{N}[o][c][k]    (round-1 proven f32 deform layout)
//  w0h[m][hid][ch]   f16 <- sN_{sc,sh}0_w      (m: s1c0,s1h0,s2c0,s2h0)
//  w1h[m][out][hid]  f16 <- sN_{sc,sh}1_w
__global__ __launch_bounds__(256) void k_prep(
    const float* __restrict__ w_off,
    const float* __restrict__ wd1,  const float* __restrict__ wd2,
    const float* __restrict__ s1c0, const float* __restrict__ s1h0,
    const float* __restrict__ s2c0, const float* __restrict__ s2h0,
    const float* __restrict__ s1c1, const float* __restrict__ s1h1,
    const float* __restrict__ s2c1, const float* __restrict__ s2h1,
    float* __restrict__ wofft, float* __restrict__ wd1t, float* __restrict__ wd2t,
    u16* __restrict__ w0h,     u16* __restrict__ w1h)
{
    int t = blockIdx.x * 256 + threadIdx.x;
    if (t < C0 * 18 * 9) {
        int c = t / 162, r = t % 162, o = r / 9, tap = r % 9;
        wofft[t] = w_off[(o * C0 + c) * 9 + tap];
    }
    if (t < 9 * C0 * C0) {
        int k = t / (C0 * C0), r = t % (C0 * C0), c = r / C0, o = r % C0;
        wd1t[t] = wd1[(o * C0 + c) * 9 + k];
        wd2t[t] = wd2[(o * C0 + c) * 9 + k];
    }
    if (t < 4 * C0 * C1) {
        int m = t / (C0 * C1), i = t % (C0 * C1);
        const float* s = (m == 0) ? s1c0 : (m == 1) ? s1h0 : (m == 2) ? s2c0 : s2h0;
        w0h[t] = f2h(s[i]);
    }
    if (t < 4 * C0 * C0) {
        int m = t / (C0 * C0), i = t % (C0 * C0);
        const float* s = (m == 0) ? s1c1 : (m == 1) ? s1h1 : (m == 2) ? s2c1 : s2h1;
        w1h[t] = f2h(s[i]);
    }
}

// ---------------------------------------------------------------------------
// Offset conv: 3x3, 128 -> 18 (f32, round-1 proven)
__global__ __launch_bounds__(256) void k_conv_off(
    const float* __restrict__ x0, const float* __restrict__ wofft,
    const float* __restrict__ boff, float* __restrict__ off)
{
    int bx = blockIdx.x;
    int b  = bx / TPB;
    int p0 = (bx % TPB) * PT;
    int tid = threadIdx.x;
    int p   = tid & 63;
    int cq  = __builtin_amdgcn_readfirstlane(tid >> 6);
    int pos = p0 + p;
    int h = pos / W_, w = pos % W_;

    float acc[18];
#pragma unroll
    for (int o = 0; o < 18; ++o) acc[o] = 0.f;

    for (int cc = 0; cc < 32; ++cc) {
        int c = cq * 32 + cc;
        const float* xb = x0 + ((size_t)(b * C0 + c)) * HW;
        float v[9];
#pragma unroll
        for (int t = 0; t < 9; ++t) {
            int dy = t / 3 - 1, dx = t % 3 - 1;
            int hy = h + dy, wx = w + dx;
            bool ok = (hy >= 0) & (hy < H_) & (wx >= 0) & (wx < W_);
            v[t] = ok ? xb[hy * W_ + wx] : 0.f;
        }
        const float* wr = wofft + c * 162;
#pragma unroll
        for (int o = 0; o < 18; ++o)
#pragma unroll
            for (int t = 0; t < 9; ++t)
                acc[o] = fmaf(wr[o * 9 + t], v[t], acc[o]);
    }

    __shared__ float red[4][18][PT];
#pragma unroll
    for (int o = 0; o < 18; ++o) red[cq][o][p] = acc[o];
    __syncthreads();
    for (int idx = tid; idx < 18 * PT; idx += 256) {
        int o = idx / PT, pp = idx % PT;
        float s = red[0][o][pp] + red[1][o][pp] + red[2][o][pp] + red[3][o][pp]
                + boff[o];
        off[((size_t)(b * 18 + o)) * HW + p0 + pp] = s;
    }
}

// ---------------------------------------------------------------------------
// Fused SFT via MFMA (f16 operands, f32 storage everywhere).
// x from f32 channel-major [B,128,HW]; output f32 position-major [B,HW,128].
__global__ __launch_bounds__(512) void k_sft_mma(
    const float* __restrict__ xf,     // [B,128,HW]
    const float* __restrict__ x1,
    const u16* __restrict__ w0s, const u16* __restrict__ w0h,   // [128 hid][32 ch]
    const u16* __restrict__ w1s, const u16* __restrict__ w1h,   // [128 out][128 hid]
    const float* __restrict__ b0s, const float* __restrict__ b0h,
    const float* __restrict__ b1s, const float* __restrict__ b1h,
    float* __restrict__ outT)         // [B,HW,128]
{
    __shared__ __align__(16) u16   x1t[64 * 32];        // 4 KB, swz 64B rows
    __shared__ __align__(16) u16   hidt[2][64 * 128];   // 32 KB, swz
    __shared__ __align__(16) float outt[64 * 128];      // 32 KB, linear

    int bx = blockIdx.x, b = bx / TPB, p0 = (bx % TPB) * PT;
    int tid = threadIdx.x, l = tid & 63;
    int w = __builtin_amdgcn_readfirstlane(tid >> 6);
    f32x4 zz = {0.f, 0.f, 0.f, 0.f};

    // Phase A: stage x1 tile (transpose to [pos][ch], f16, swizzled)
    for (int i = tid; i < C1 * PT; i += 512) {
        int ch = i >> 6, pos = i & 63;
        float v = x1[((size_t)(b * C1 + ch)) * HW + p0 + pos];
        x1t[pos * 32 + (ch ^ ((pos & 3) << 3))] = f2h(v);
    }
    __syncthreads();

    // Phase B: hidden GEMM (K=32, one k-step).  wave: mt=w&3, br=w>>2.
    {
        int mt = w & 3, br = w >> 2;
        int pos = mt * 16 + (l & 15);
        int koff = (l >> 4) * 8;
        f16x8 a = *(const f16x8*)&x1t[pos * 32 + (koff ^ ((pos & 3) << 3))];
        const u16* w0 = br ? w0h : w0s;
        const float* bb = br ? b0h : b0s;
        u16* hrow = hidt[br];
#pragma unroll
        for (int nt = 0; nt < 8; ++nt) {
            int n = nt * 16 + (l & 15);
            f16x8 bfr = *(const f16x8*)&w0[n * 32 + koff];
            f32x4 h = __builtin_amdgcn_mfma_f32_16x16x32_f16(a, bfr, zz, 0, 0, 0);
            float bv = bb[n];
#pragma unroll
            for (int r = 0; r < 4; ++r) {
                float hv = h[r] + bv;
                hv = hv > 0.f ? hv : 0.1f * hv;
                int prow = mt * 16 + (l >> 4) * 4 + r;
                hrow[prow * 128 + (n ^ ((prow & 7) << 3))] = f2h(hv);
            }
        }
    }
    __syncthreads();

    // Phase C: second GEMM, both branches.  wave: mt=w&3, nh=w>>2.
    f32x4 accS[4], accH[4];
#pragma unroll
    for (int nt = 0; nt < 4; ++nt) { accS[nt] = zz; accH[nt] = zz; }
    int mt = w & 3, nh = w >> 2;
    int pos = mt * 16 + (l & 15);
#pragma unroll
    for (int ks = 0; ks < 4; ++ks) {
        int kb = ks * 32 + (l >> 4) * 8;
        f16x8 aS = *(const f16x8*)&hidt[0][pos * 128 + (kb ^ ((pos & 7) << 3))];
        f16x8 aH = *(const f16x8*)&hidt[1][pos * 128 + (kb ^ ((pos & 7) << 3))];
#pragma unroll
        for (int nt = 0; nt < 4; ++nt) {
            int n = nh * 64 + nt * 16 + (l & 15);
            f16x8 bS = *(const f16x8*)&w1s[n * 128 + kb];
            f16x8 bH = *(const f16x8*)&w1h[n * 128 + kb];
            accS[nt] = __builtin_amdgcn_mfma_f32_16x16x32_f16(aS, bS, accS[nt], 0, 0, 0);
            accH[nt] = __builtin_amdgcn_mfma_f32_16x16x32_f16(aH, bH, accH[nt], 0, 0, 0);
        }
    }

    // Phase D: epilogue  out = x*(scale+1)+shift  -> outt (f32 [pos][out])
#pragma unroll
    for (int nt = 0; nt < 4; ++nt) {
        int n = nh * 64 + nt * 16 + (l & 15);
        float scb = b1s[n], shb = b1h[n];
        const float* xp = xf + ((size_t)(b * C0 + n)) * HW + p0 + mt * 16 + (l >> 4) * 4;
        f32x4 x4 = *(const f32x4*)xp;
#pragma unroll
        for (int r = 0; r < 4; ++r) {
            float scale = accS[nt][r] + scb + 1.f;
            float shift = accH[nt][r] + shb;
            outt[(mt * 16 + (l >> 4) * 4 + r) * 128 + n] = x4[r] * scale + shift;
        }
    }
    __syncthreads();

    // coalesced writeback: 32 KB contiguous f32
    float* dst = outT + ((size_t)(b * HW + p0)) * C0;
    for (int i = tid; i < 2048; i += 512)
        *(f32x4*)&dst[i * 4] = *(const f32x4*)&outt[i * 4];
}

// ---------------------------------------------------------------------------
// Deformable conv 3x3, f32 VALU (round-1 proven math).  Gather source is
// position-major f32 [B,HW,128] (vectorized loads).  MODE 0: ReLU -> f32
// channel-major [B,128,HW].  MODE 1: + bias + x0 residual -> d_out.
template <int MODE>
__global__ __launch_bounds__(512) void k_deform_f32(
    const float* __restrict__ srcT,  // [B,HW,128] f32
    const float* __restrict__ off,   // [B,18,HW]
    const float* __restrict__ wdt,   // [9][128 c][128 o] f32
    const float* __restrict__ bias,
    const float* __restrict__ x0,    // MODE 1 residual
    float* __restrict__ out)         // [B,128,HW]
{
    __shared__ float samp[C0][PT];   // 32 KB
    __shared__ int   acy[9][PT];
    __shared__ int   acx[9][PT];
    __shared__ float awy[9][PT];
    __shared__ float awx[9][PT];

    int bx = blockIdx.x;
    int b  = bx / TPB;
    int p0 = (bx % TPB) * PT;
    int tid = threadIdx.x;
    int p   = tid & 63;
    int g   = __builtin_amdgcn_readfirstlane(tid >> 6);   // 0..7

    for (int idx = tid; idx < 9 * PT; idx += 512) {
        int k = idx >> 6, pp = idx & 63;
        int pos = p0 + pp;
        int h = pos / W_, w = pos % W_;
        float dy = off[((size_t)(b * 18 + 2 * k)) * HW + pos];
        float dx = off[((size_t)(b * 18 + 2 * k + 1)) * HW + pos];
        float py = dy + (float)(h + k / 3 - 1);
        float px = dx + (float)(w + k % 3 - 1);
        float y0f = floorf(py), x0f = floorf(px);
        acy[k][pp] = (int)y0f;
        acx[k][pp] = (int)x0f;
        awy[k][pp] = py - y0f;
        awx[k][pp] = px - x0f;
    }
    __syncthreads();

    float acc[16];
#pragma unroll
    for (int i = 0; i < 16; ++i) acc[i] = 0.f;

    const float* base = srcT + (size_t)b * HW * C0 + g * 16;

    for (int k = 0; k < 9; ++k) {
        int   y0 = acy[k][p], xi = acx[k][p];
        float wy = awy[k][p], wx = awx[k][p];
        bool vy0 = (y0 >= 0) & (y0 < H_);
        bool vy1 = (y0 + 1 >= 0) & (y0 + 1 < H_);
        bool vx0 = (xi >= 0) & (xi < W_);
        bool vx1 = (xi + 1 >= 0) & (xi + 1 < W_);
        float w00 = (vy0 & vx0) ? (1.f - wy) * (1.f - wx) : 0.f;
        float w01 = (vy0 & vx1) ? (1.f - wy) * wx         : 0.f;
        float w10 = (vy1 & vx0) ? wy * (1.f - wx)         : 0.f;
        float w11 = (vy1 & vx1) ? wy * wx                 : 0.f;
        int iy0 = min(max(y0, 0), H_ - 1),     iy1 = min(max(y0 + 1, 0), H_ - 1);
        int ix0 = min(max(xi, 0), W_ - 1),     ix1 = min(max(xi + 1, 0), W_ - 1);
        const float* q00 = base + (size_t)(iy0 * W_ + ix0) * C0;
        const float* q01 = base + (size_t)(iy0 * W_ + ix1) * C0;
        const float* q10 = base + (size_t)(iy1 * W_ + ix0) * C0;
        const float* q11 = base + (size_t)(iy1 * W_ + ix1) * C0;
#pragma unroll
        for (int q = 0; q < 4; ++q) {
            f32x4 v00 = *(const f32x4*)(q00 + q * 4);
            f32x4 v01 = *(const f32x4*)(q01 + q * 4);
            f32x4 v10 = *(const f32x4*)(q10 + q * 4);
            f32x4 v11 = *(const f32x4*)(q11 + q * 4);
#pragma unroll
            for (int e = 0; e < 4; ++e)
                samp[g * 16 + q * 4 + e][p] =
                    v00[e] * w00 + v01[e] * w01 + v10[e] * w10 + v11[e] * w11;
        }
        __syncthreads();

        // Accumulate phase: weight-stationary, 16 outputs per thread (round-1)
        const float* wk = wdt + (size_t)k * C0 * C0 + g * 16;
        for (int c = 0; c < C0; ++c) {
            float s = samp[c][p];
            const float* wr = wk + c * C0;   // uniform -> s_load_dwordx16
#pragma unroll
            for (int i = 0; i < 16; ++i) acc[i] = fmaf(wr[i], s, acc[i]);
        }
        __syncthreads();
    }

#pragma unroll
    for (int i = 0; i < 16; ++i) {
        int o = g * 16 + i;
        float v = acc[i] + bias[o];
        size_t oi = ((size_t)(b * C0 + o)) * HW + p0 + p;
        if (MODE == 0) v = v > 0.f ? v : 0.f;
        else           v += x0[oi];
        out[oi] = v;
    }
}

// ---------------------------------------------------------------------------
// Workspace layout (bytes)
constexpr size_t WB_OFF   = 0;            // f32 [B,18,HW]       2,654,208
constexpr size_t WB_WOFFT = 2654208;      // f32 [128][162]         82,944
constexpr size_t WB_W0H   = 2737152;      // f16 [4][128][32]       32,768
constexpr size_t WB_W1H   = 2769920;      // f16 [4][128][128]     131,072
constexpr size_t WB_WD1T  = 2900992;      // f32 [9][128][128]     589,824
constexpr size_t WB_WD2T  = 3490816;      // f32 [9][128][128]     589,824
constexpr size_t WB_TA    = 4080640;      // f32 [B,HW,128]     18,874,368
constexpr size_t WB_TB    = 22955008;     // f32 [B,128,HW]     18,874,368
// total 41,829,376 B

extern "C" void kernel_launch(void* const* d_in, const int* in_sizes, int n_in,
                              void* d_out, int out_size, void* d_ws, size_t ws_size,
                              hipStream_t stream)
{
    const float* x0      = (const float*)d_in[0];
    const float* x1      = (const float*)d_in[1];
    const float* w_off   = (const float*)d_in[2];
    const float* b_off   = (const float*)d_in[3];
    const float* s1_sc0w = (const float*)d_in[4];
    const float* s1_sc0b = (const float*)d_in[5];
    const float* s1_sc1w = (const float*)d_in[6];
    const float* s1_sc1b = (const float*)d_in[7];
    const float* s1_sh0w = (const float*)d_in[8];
    const float* s1_sh0b = (const float*)d_in[9];
    const float* s1_sh1w = (const float*)d_in[10];
    const float* s1_sh1b = (const float*)d_in[11];
    const float* w_d1    = (const float*)d_in[12];
    const float* b_d1    = (const float*)d_in[13];
    const float* s2_sc0w = (const float*)d_in[14];
    const float* s2_sc0b = (const float*)d_in[15];
    const float* s2_sc1w = (const float*)d_in[16];
    const float* s2_sc1b = (const float*)d_in[17];
    const float* s2_sh0w = (const float*)d_in[18];
    const float* s2_sh0b = (const float*)d_in[19];
    const float* s2_sh1w = (const float*)d_in[20];
    const float* s2_sh1b = (const float*)d_in[21];
    const float* w_d2    = (const float*)d_in[22];
    const float* b_d2    = (const float*)d_in[23];

    char* wsb = (char*)d_ws;
    float* off   = (float*)(wsb + WB_OFF);
    float* wofft = (float*)(wsb + WB_WOFFT);
    u16*   w0h   = (u16*)(wsb + WB_W0H);
    u16*   w1h   = (u16*)(wsb + WB_W1H);
    float* wd1t  = (float*)(wsb + WB_WD1T);
    float* wd2t  = (float*)(wsb + WB_WD2T);
    float* TA    = (float*)(wsb + WB_TA);
    float* TB    = (float*)(wsb + WB_TB);

    k_prep<<<576, 256, 0, stream>>>(w_off, w_d1, w_d2,
                                    s1_sc0w, s1_sh0w, s2_sc0w, s2_sh0w,
                                    s1_sc1w, s1_sh1w, s2_sc1w, s2_sh1w,
                                    wofft, wd1t, wd2t, w0h, w1h);
    k_conv_off<<<NTILE, 256, 0, stream>>>(x0, wofft, b_off, off);
    // SFT1: x = x0 (channel-major) -> TA (position-major)
    k_sft_mma<<<NTILE, 512, 0, stream>>>(x0, x1,
                                         w0h, w0h + 4096,
                                         w1h, w1h + 16384,
                                         s1_sc0b, s1_sh0b, s1_sc1b, s1_sh1b, TA);
    // dconv1 (f32): gather TA -> relu -> TB (channel-major)
    k_deform_f32<0><<<NTILE, 512, 0, stream>>>(TA, off, wd1t, b_d1, nullptr, TB);
    // SFT2: x = TB (channel-major) -> TA (position-major)
    k_sft_mma<<<NTILE, 512, 0, stream>>>(TB, x1,
                                         w0h + 8192, w0h + 12288,
                                         w1h + 32768, w1h + 49152,
                                         s2_sc0b, s2_sh0b, s2_sc1b, s2_sh1b, TA);
    // dconv2 (f32): gather TA -> +bias +x0 -> d_out
    k_deform_f32<1><<<NTILE, 512, 0, stream>>>(TA, off, wd2t, b_d2, x0, (float*)d_out);
}

// Round 8
// 402.308 us; speedup vs baseline: 1.7262x; 1.7262x over previous
//
#include <hip/hip_runtime.h>

typedef unsigned short u16;
typedef unsigned int   u32;
typedef __attribute__((ext_vector_type(8))) _Float16 f16x8;
typedef __attribute__((ext_vector_type(2))) float f32x2;
typedef __attribute__((ext_vector_type(4))) float f32x4;
typedef __attribute__((ext_vector_type(4))) unsigned int u32x4;

constexpr int B_  = 4;
constexpr int C0  = 128;
constexpr int C1  = 32;
constexpr int H_  = 96;
constexpr int W_  = 96;
constexpr int HW  = H_ * W_;        // 9216
constexpr int PT  = 64;
constexpr int TPB = HW / PT;        // 144
constexpr int NTILE = B_ * TPB;     // 576

__device__ inline u16 f2h(float f) {
    _Float16 h = (_Float16)f;
    return __builtin_bit_cast(u16, h);
}

// ---------------------------------------------------------------------------
// Weight prep:
//  wofft[c][o*9+t]        f32       <- w_off[o][c][t]
//  wdhi/wdlo[d][k][o][c]  f16 split <- w_d{d}[o][c][k]   (hi + residual)
//  w0h[m][hid][ch]        f16       <- sN_{sc,sh}0_w
//  w1h[m][out][hid]       f16       <- sN_{sc,sh}1_w
__global__ __launch_bounds__(256) void k_prep(
    const float* __restrict__ w_off,
    const float* __restrict__ wd1,  const float* __restrict__ wd2,
    const float* __restrict__ s1c0, const float* __restrict__ s1h0,
    const float* __restrict__ s2c0, const float* __restrict__ s2h0,
    const float* __restrict__ s1c1, const float* __restrict__ s1h1,
    const float* __restrict__ s2c1, const float* __restrict__ s2h1,
    float* __restrict__ wofft, u16* __restrict__ wdhi, u16* __restrict__ wdlo,
    u16* __restrict__ w0h,     u16* __restrict__ w1h)
{
    int t = blockIdx.x * 256 + threadIdx.x;
    if (t < C0 * 18 * 9) {
        int c = t / 162, r = t % 162, o = r / 9, tap = r % 9;
        wofft[t] = w_off[(o * C0 + c) * 9 + tap];
    }
    if (t < 2 * 9 * C0 * C0) {
        int d = t / (9 * C0 * C0), r = t % (9 * C0 * C0);
        int k = r / (C0 * C0), r2 = r % (C0 * C0), o = r2 / C0, c = r2 % C0;
        const float* wsrc = d ? wd2 : wd1;
        float wv = wsrc[(o * C0 + c) * 9 + k];
        _Float16 hi = (_Float16)wv;
        float rr = wv - (float)hi;
        wdhi[t] = __builtin_bit_cast(u16, hi);
        wdlo[t] = f2h(rr);
    }
    if (t < 4 * C0 * C1) {
        int m = t / (C0 * C1), i = t % (C0 * C1);
        const float* s = (m == 0) ? s1c0 : (m == 1) ? s1h0 : (m == 2) ? s2c0 : s2h0;
        w0h[t] = f2h(s[i]);
    }
    if (t < 4 * C0 * C0) {
        int m = t / (C0 * C0), i = t % (C0 * C0);
        const float* s = (m == 0) ? s1c1 : (m == 1) ? s1h1 : (m == 2) ? s2c1 : s2h1;
        w1h[t] = f2h(s[i]);
    }
}

// ---------------------------------------------------------------------------
// Offset conv: 3x3, 128 -> 18 (f32, round-1 proven)
__global__ __launch_bounds__(256) void k_conv_off(
    const float* __restrict__ x0, const float* __restrict__ wofft,
    const float* __restrict__ boff, float* __restrict__ off)
{
    int bx = blockIdx.x;
    int b  = bx / TPB;
    int p0 = (bx % TPB) * PT;
    int tid = threadIdx.x;
    int p   = tid & 63;
    int cq  = __builtin_amdgcn_readfirstlane(tid >> 6);
    int pos = p0 + p;
    int h = pos / W_, w = pos % W_;

    float acc[18];
#pragma unroll
    for (int o = 0; o < 18; ++o) acc[o] = 0.f;

    for (int cc = 0; cc < 32; ++cc) {
        int c = cq * 32 + cc;
        const float* xb = x0 + ((size_t)(b * C0 + c)) * HW;
        float v[9];
#pragma unroll
        for (int t = 0; t < 9; ++t) {
            int dy = t / 3 - 1, dx = t % 3 - 1;
            int hy = h + dy, wx = w + dx;
            bool ok = (hy >= 0) & (hy < H_) & (wx >= 0) & (wx < W_);
            v[t] = ok ? xb[hy * W_ + wx] : 0.f;
        }
        const float* wr = wofft + c * 162;
#pragma unroll
        for (int o = 0; o < 18; ++o)
#pragma unroll
            for (int t = 0; t < 9; ++t)
                acc[o] = fmaf(wr[o * 9 + t], v[t], acc[o]);
    }

    __shared__ float red[4][18][PT];
#pragma unroll
    for (int o = 0; o < 18; ++o) red[cq][o][p] = acc[o];
    __syncthreads();
    for (int idx = tid; idx < 18 * PT; idx += 256) {
        int o = idx / PT, pp = idx % PT;
        float s = red[0][o][pp] + red[1][o][pp] + red[2][o][pp] + red[3][o][pp]
                + boff[o];
        off[((size_t)(b * 18 + o)) * HW + p0 + pp] = s;
    }
}

// ---------------------------------------------------------------------------
// Fused SFT via MFMA (f16 operands, f32 storage).  XSRC 0: x f32 [B,128,HW];
// XSRC 1: x f32 [B,HW,128].  Output: f32 [B,HW,128].
template <int XSRC>
__global__ __launch_bounds__(512) void k_sft_mma(
    const float* __restrict__ xf,     // XSRC==0
    const float* __restrict__ xT,     // XSRC==1
    const float* __restrict__ x1,
    const u16* __restrict__ w0s, const u16* __restrict__ w0h,   // [128 hid][32 ch]
    const u16* __restrict__ w1s, const u16* __restrict__ w1h,   // [128 out][128 hid]
    const float* __restrict__ b0s, const float* __restrict__ b0h,
    const float* __restrict__ b1s, const float* __restrict__ b1h,
    float* __restrict__ outT)         // [B,HW,128]
{
    __shared__ __align__(16) u16   x1t[64 * 32];
    __shared__ __align__(16) u16   hidt[2][64 * 128];
    __shared__ __align__(16) float outt[64 * 128];

    int bx = blockIdx.x, b = bx / TPB, p0 = (bx % TPB) * PT;
    int tid = threadIdx.x, l = tid & 63;
    int w = __builtin_amdgcn_readfirstlane(tid >> 6);
    f32x4 zz = {0.f, 0.f, 0.f, 0.f};

    for (int i = tid; i < C1 * PT; i += 512) {
        int ch = i >> 6, pos = i & 63;
        float v = x1[((size_t)(b * C1 + ch)) * HW + p0 + pos];
        x1t[pos * 32 + (ch ^ ((pos & 3) << 3))] = f2h(v);
    }
    __syncthreads();

    {   // hidden GEMM (K=32)
        int mt = w & 3, br = w >> 2;
        int pos = mt * 16 + (l & 15);
        int koff = (l >> 4) * 8;
        f16x8 a = *(const f16x8*)&x1t[pos * 32 + (koff ^ ((pos & 3) << 3))];
        const u16* w0 = br ? w0h : w0s;
        const float* bb = br ? b0h : b0s;
        u16* hrow = hidt[br];
#pragma unroll
        for (int nt = 0; nt < 8; ++nt) {
            int n = nt * 16 + (l & 15);
            f16x8 bfr = *(const f16x8*)&w0[n * 32 + koff];
            f32x4 h = __builtin_amdgcn_mfma_f32_16x16x32_f16(a, bfr, zz, 0, 0, 0);
            float bv = bb[n];
#pragma unroll
            for (int r = 0; r < 4; ++r) {
                float hv = h[r] + bv;
                hv = hv > 0.f ? hv : 0.1f * hv;
                int prow = mt * 16 + (l >> 4) * 4 + r;
                hrow[prow * 128 + (n ^ ((prow & 7) << 3))] = f2h(hv);
            }
        }
    }
    __syncthreads();

    f32x4 accS[4], accH[4];
#pragma unroll
    for (int nt = 0; nt < 4; ++nt) { accS[nt] = zz; accH[nt] = zz; }
    int mt = w & 3, nh = w >> 2;
    int pos = mt * 16 + (l & 15);
#pragma unroll
    for (int ks = 0; ks < 4; ++ks) {
        int kb = ks * 32 + (l >> 4) * 8;
        f16x8 aS = *(const f16x8*)&hidt[0][pos * 128 + (kb ^ ((pos & 7) << 3))];
        f16x8 aH = *(const f16x8*)&hidt[1][pos * 128 + (kb ^ ((pos & 7) << 3))];
#pragma unroll
        for (int nt = 0; nt < 4; ++nt) {
            int n = nh * 64 + nt * 16 + (l & 15);
            f16x8 bS = *(const f16x8*)&w1s[n * 128 + kb];
            f16x8 bH = *(const f16x8*)&w1h[n * 128 + kb];
            accS[nt] = __builtin_amdgcn_mfma_f32_16x16x32_f16(aS, bS, accS[nt], 0, 0, 0);
            accH[nt] = __builtin_amdgcn_mfma_f32_16x16x32_f16(aH, bH, accH[nt], 0, 0, 0);
        }
    }

#pragma unroll
    for (int nt = 0; nt < 4; ++nt) {
        int n = nh * 64 + nt * 16 + (l & 15);
        float scb = b1s[n], shb = b1h[n];
        float xv[4];
        if (XSRC == 0) {
            const float* xp = xf + ((size_t)(b * C0 + n)) * HW + p0 + mt * 16 + (l >> 4) * 4;
            f32x4 x4 = *(const f32x4*)xp;
#pragma unroll
            for (int r = 0; r < 4; ++r) xv[r] = x4[r];
        } else {
#pragma unroll
            for (int r = 0; r < 4; ++r)
                xv[r] = xT[((size_t)(b * HW + p0 + mt * 16 + (l >> 4) * 4 + r)) * C0 + n];
        }
#pragma unroll
        for (int r = 0; r < 4; ++r) {
            float scale = accS[nt][r] + scb + 1.f;
            float shift = accH[nt][r] + shb;
            outt[(mt * 16 + (l >> 4) * 4 + r) * 128 + n] = xv[r] * scale + shift;
        }
    }
    __syncthreads();

    float* dst = outT + ((size_t)(b * HW + p0)) * C0;
    for (int i = tid; i < 2048; i += 512)
        *(f32x4*)&dst[i * 4] = *(const f32x4*)&outt[i * 4];
}

// ---------------------------------------------------------------------------
// Deformable conv 3x3 via split-f16 MFMA (3-term, ~f32 precision).
// MODE 0: ReLU -> f32 [B,HW,128].  MODE 1: + bias + x0 -> f32 [B,128,HW].
template <int MODE>
__global__ __launch_bounds__(512) void k_deform3(
    const float* __restrict__ srcT,  // [B,HW,128] f32
    const float* __restrict__ off,   // [B,18,HW]
    const u16* __restrict__ whi,     // [9][128 o][128 c] f16 hi
    const u16* __restrict__ wlo,     // [9][128 o][128 c] f16 lo
    const float* __restrict__ bias,
    const float* __restrict__ x0,
    float* __restrict__ outF,        // MODE 1
    float* __restrict__ outT)        // MODE 0
{
    __shared__ __align__(16) u16 sm[4][64 * 128];   // 64 KB total
    u16* a_hi = sm[0];  u16* a_lo = sm[1];
    u16* b_hi = sm[2];  u16* b_lo = sm[3];

    int bx = blockIdx.x;
    bx = (bx & 7) * (NTILE / 8) + (bx >> 3);        // XCD swizzle (576%8==0)
    int b = bx / TPB, p0 = (bx % TPB) * PT;
    int tid = threadIdx.x, l = tid & 63;
    int w = __builtin_amdgcn_readfirstlane(tid >> 6);
    f32x4 zz = {0.f, 0.f, 0.f, 0.f};

    f32x4 acc[2][2];
#pragma unroll
    for (int hf = 0; hf < 2; ++hf)
#pragma unroll
        for (int nt = 0; nt < 2; ++nt) acc[hf][nt] = zz;

    int mt = w & 3, ng = w >> 2;          // MFMA: 4 m-tiles x 2 n-groups
    int pos_r = mt * 16 + (l & 15);
    const float* base = srcT + (size_t)b * HW * C0;
    int so = tid >> 3, sp = tid & 7;      // B staging: o-row, 16-ch part

    for (int k = 0; k < 9; ++k) {
        // ---- Phase 1: gather A (wave w -> positions w*8..w*8+7)
        for (int i = 0; i < 8; ++i) {
            int pp = w * 8 + i;
            int pos = p0 + pp;
            int h = pos / W_, wc = pos % W_;
            float dy = off[((size_t)(b * 18 + 2 * k)) * HW + pos];
            float dx = off[((size_t)(b * 18 + 2 * k + 1)) * HW + pos];
            float py = dy + (float)(h + k / 3 - 1);
            float px = dx + (float)(wc + k % 3 - 1);
            float yf = floorf(py), xf = floorf(px);
            int y0 = (int)yf, x0i = (int)xf;
            float wy = py - yf, wx = px - xf;
            bool vy0 = (y0 >= 0) & (y0 < H_), vy1 = (y0 + 1 >= 0) & (y0 + 1 < H_);
            bool vx0 = (x0i >= 0) & (x0i < W_), vx1 = (x0i + 1 >= 0) & (x0i + 1 < W_);
            float w00 = (vy0 & vx0) ? (1.f - wy) * (1.f - wx) : 0.f;
            float w01 = (vy0 & vx1) ? (1.f - wy) * wx         : 0.f;
            float w10 = (vy1 & vx0) ? wy * (1.f - wx)         : 0.f;
            float w11 = (vy1 & vx1) ? wy * wx                 : 0.f;
            int iy0 = min(max(y0, 0), H_ - 1), iy1 = min(max(y0 + 1, 0), H_ - 1);
            int ix0 = min(max(x0i, 0), W_ - 1), ix1 = min(max(x0i + 1, 0), W_ - 1);
            const float* q00 = base + (size_t)(iy0 * W_ + ix0) * C0 + 2 * l;
            const float* q01 = base + (size_t)(iy0 * W_ + ix1) * C0 + 2 * l;
            const float* q10 = base + (size_t)(iy1 * W_ + ix0) * C0 + 2 * l;
            const float* q11 = base + (size_t)(iy1 * W_ + ix1) * C0 + 2 * l;
            f32x2 v00 = *(const f32x2*)q00;
            f32x2 v01 = *(const f32x2*)q01;
            f32x2 v10 = *(const f32x2*)q10;
            f32x2 v11 = *(const f32x2*)q11;
            float s0 = v00[0] * w00 + v01[0] * w01 + v10[0] * w10 + v11[0] * w11;
            float s1 = v00[1] * w00 + v01[1] * w01 + v10[1] * w10 + v11[1] * w11;
            _Float16 h0 = (_Float16)s0, h1 = (_Float16)s1;
            float r0 = s0 - (float)h0, r1 = s1 - (float)h1;
            u32 hv = (u32)__builtin_bit_cast(u16, h0) | ((u32)__builtin_bit_cast(u16, h1) << 16);
            u32 lv = (u32)f2h(r0) | ((u32)f2h(r1) << 16);
            int ci = (2 * l) ^ ((pp & 7) << 3);
            *(u32*)&a_hi[pp * 128 + ci] = hv;
            *(u32*)&a_lo[pp * 128 + ci] = lv;
        }

#pragma unroll
        for (int hf = 0; hf < 2; ++hf) {
            {   // stage B half hf: rows hf*64+so, 32B per thread per array
                int orow = hf * 64 + so;
                const u16* sh = whi + ((size_t)k * C0 + orow) * C0 + sp * 16;
                const u16* sl = wlo + ((size_t)k * C0 + orow) * C0 + sp * 16;
                int sw = (so & 7) << 3;
#pragma unroll
                for (int j = 0; j < 2; ++j) {
                    int cj = (sp * 16 + j * 8) ^ sw;
                    *(u32x4*)&b_hi[so * 128 + cj] = *(const u32x4*)&sh[j * 8];
                    *(u32x4*)&b_lo[so * 128 + cj] = *(const u32x4*)&sl[j * 8];
                }
            }
            __syncthreads();
#pragma unroll
            for (int ks = 0; ks < 4; ++ks) {
                int kb = ks * 32 + (l >> 4) * 8;
                int ai = pos_r * 128 + (kb ^ ((pos_r & 7) << 3));
                f16x8 ah = *(const f16x8*)&a_hi[ai];
                f16x8 al = *(const f16x8*)&a_lo[ai];
#pragma unroll
                for (int nt = 0; nt < 2; ++nt) {
                    int orow = ng * 32 + nt * 16 + (l & 15);
                    int bi = orow * 128 + (kb ^ ((orow & 7) << 3));
                    f16x8 bh = *(const f16x8*)&b_hi[bi];
                    f16x8 bl = *(const f16x8*)&b_lo[bi];
                    acc[hf][nt] = __builtin_amdgcn_mfma_f32_16x16x32_f16(ah, bh, acc[hf][nt], 0, 0, 0);
                    acc[hf][nt] = __builtin_amdgcn_mfma_f32_16x16x32_f16(al, bh, acc[hf][nt], 0, 0, 0);
                    acc[hf][nt] = __builtin_amdgcn_mfma_f32_16x16x32_f16(ah, bl, acc[hf][nt], 0, 0, 0);
                }
            }
            __syncthreads();
        }
    }

    if (MODE == 0) {
        // ReLU -> f32 tile over sm[0..1] (32 KB), then coalesced writeback
        float* otile = (float*)sm;
#pragma unroll
        for (int hf = 0; hf < 2; ++hf)
#pragma unroll
            for (int nt = 0; nt < 2; ++nt) {
                int o = hf * 64 + ng * 32 + nt * 16 + (l & 15);
                float bv = bias[o];
#pragma unroll
                for (int r = 0; r < 4; ++r) {
                    float v = acc[hf][nt][r] + bv;
                    v = v > 0.f ? v : 0.f;
                    otile[(mt * 16 + (l >> 4) * 4 + r) * 128 + o] = v;
                }
            }
        __syncthreads();
        float* dst = outT + ((size_t)(b * HW + p0)) * C0;
        for (int i = tid; i < 2048; i += 512)
            *(f32x4*)&dst[i * 4] = *(const f32x4*)&otile[i * 4];
    } else {
#pragma unroll
        for (int hf = 0; hf < 2; ++hf)
#pragma unroll
            for (int nt = 0; nt < 2; ++nt) {
                int o = hf * 64 + ng * 32 + nt * 16 + (l & 15);
                float bv = bias[o];
                size_t base_o = ((size_t)(b * C0 + o)) * HW + p0 + mt * 16 + (l >> 4) * 4;
                f32x4 x4 = *(const f32x4*)(x0 + base_o);
                f32x4 ov;
#pragma unroll
                for (int r = 0; r < 4; ++r) ov[r] = acc[hf][nt][r] + bv + x4[r];
                *(f32x4*)(outF + base_o) = ov;
            }
    }
}

// ---------------------------------------------------------------------------
// Workspace layout (bytes)
constexpr size_t WB_OFF   = 0;            // f32 [B,18,HW]        2,654,208
constexpr size_t WB_WOFFT = 2654208;      // f32 [128][162]          82,944
constexpr size_t WB_W0H   = 2737152;      // f16 [4][128][32]        32,768
constexpr size_t WB_W1H   = 2769920;      // f16 [4][128][128]      131,072
constexpr size_t WB_WDHI  = 2900992;      // f16 [2][9][128][128] 1,179,648
constexpr size_t WB_WDLO  = 4080640;      // f16 [2][9][128][128] 1,179,648
constexpr size_t WB_TA    = 5260288;      // f32 [B,HW,128]      18,874,368
constexpr size_t WB_TB    = 24134656;     // f32 [B,HW,128]      18,874,368
// total 43,009,024 B

extern "C" void kernel_launch(void* const* d_in, const int* in_sizes, int n_in,
                              void* d_out, int out_size, void* d_ws, size_t ws_size,
                              hipStream_t stream)
{
    const float* x0      = (const float*)d_in[0];
    const float* x1      = (const float*)d_in[1];
    const float* w_off   = (const float*)d_in[2];
    const float* b_off   = (const float*)d_in[3];
    const float* s1_sc0w = (const float*)d_in[4];
    const float* s1_sc0b = (const float*)d_in[5];
    const float* s1_sc1w = (const float*)d_in[6];
    const float* s1_sc1b = (const float*)d_in[7];
    const float* s1_sh0w = (const float*)d_in[8];
    const float* s1_sh0b = (const float*)d_in[9];
    const float* s1_sh1w = (const float*)d_in[10];
    const float* s1_sh1b = (const float*)d_in[11];
    const float* w_d1    = (const float*)d_in[12];
    const float* b_d1    = (const float*)d_in[13];
    const float* s2_sc0w = (const float*)d_in[14];
    const float* s2_sc0b = (const float*)d_in[15];
    const float* s2_sc1w = (const float*)d_in[16];
    const float* s2_sc1b = (const float*)d_in[17];
    const float* s2_sh0w = (const float*)d_in[18];
    const float* s2_sh0b = (const float*)d_in[19];
    const float* s2_sh1w = (const float*)d_in[20];
    const float* s2_sh1b = (const float*)d_in[21];
    const float* w_d2    = (const float*)d_in[22];
    const float* b_d2    = (const float*)d_in[23];

    char* wsb = (char*)d_ws;
    float* off   = (float*)(wsb + WB_OFF);
    float* wofft = (float*)(wsb + WB_WOFFT);
    u16*   w0h   = (u16*)(wsb + WB_W0H);
    u16*   w1h   = (u16*)(wsb + WB_W1H);
    u16*   wdhi  = (u16*)(wsb + WB_WDHI);
    u16*   wdlo  = (u16*)(wsb + WB_WDLO);
    float* TA    = (float*)(wsb + WB_TA);
    float* TB    = (float*)(wsb + WB_TB);

    k_prep<<<1152, 256, 0, stream>>>(w_off, w_d1, w_d2,
                                     s1_sc0w, s1_sh0w, s2_sc0w, s2_sh0w,
                                     s1_sc1w, s1_sh1w, s2_sc1w, s2_sh1w,
                                     wofft, wdhi, wdlo, w0h, w1h);
    k_conv_off<<<NTILE, 256, 0, stream>>>(x0, wofft, b_off, off);
    // SFT1: x = x0 (channel-major) -> TA (position-major)
    k_sft_mma<0><<<NTILE, 512, 0, stream>>>(x0, nullptr, x1,
                                            w0h, w0h + 4096,
                                            w1h, w1h + 16384,
                                            s1_sc0b, s1_sh0b, s1_sc1b, s1_sh1b, TA);
    // dconv1 (split-f16 MFMA): gather TA -> relu -> TB (position-major)
    k_deform3<0><<<NTILE, 512, 0, stream>>>(TA, off, wdhi, wdlo, b_d1,
                                            nullptr, nullptr, TB);
    // SFT2: x = TB (position-major) -> TA (position-major)
    k_sft_mma<1><<<NTILE, 512, 0, stream>>>(nullptr, TB, x1,
                                            w0h + 8192, w0h + 12288,
                                            w1h + 32768, w1h + 49152,
                                            s2_sc0b, s2_sh0b, s2_sc1b, s2_sh1b, TA);
    // dconv2 (split-f16 MFMA): gather TA -> +bias +x0 -> d_out (channel-major)
    k_deform3<1><<<NTILE, 512, 0, stream>>>(TA, off, wdhi + 9 * 16384, wdlo + 9 * 16384,
                                            b_d2, x0, (float*)d_out, nullptr);
}

// Round 9
// 373.319 us; speedup vs baseline: 1.8602x; 1.0777x over previous
//
#include <hip/hip_runtime.h>

typedef unsigned short u16;
typedef unsigned int   u32;
typedef __attribute__((ext_vector_type(8))) _Float16 f16x8;
typedef __attribute__((ext_vector_type(2))) float f32x2;
typedef __attribute__((ext_vector_type(4))) float f32x4;
typedef __attribute__((ext_vector_type(4))) unsigned int u32x4;

constexpr int B_  = 4;
constexpr int C0  = 128;
constexpr int C1  = 32;
constexpr int H_  = 96;
constexpr int W_  = 96;
constexpr int HW  = H_ * W_;        // 9216
constexpr int PT  = 64;
constexpr int TPB = HW / PT;        // 144
constexpr int NTILE = B_ * TPB;     // 576

__device__ inline u16 f2h(float f) {
    _Float16 h = (_Float16)f;
    return __builtin_bit_cast(u16, h);
}

// ---------------------------------------------------------------------------
// Weight prep (unchanged from round 8)
__global__ __launch_bounds__(256) void k_prep(
    const float* __restrict__ w_off,
    const float* __restrict__ wd1,  const float* __restrict__ wd2,
    const float* __restrict__ s1c0, const float* __restrict__ s1h0,
    const float* __restrict__ s2c0, const float* __restrict__ s2h0,
    const float* __restrict__ s1c1, const float* __restrict__ s1h1,
    const float* __restrict__ s2c1, const float* __restrict__ s2h1,
    float* __restrict__ wofft, u16* __restrict__ wdhi, u16* __restrict__ wdlo,
    u16* __restrict__ w0h,     u16* __restrict__ w1h)
{
    int t = blockIdx.x * 256 + threadIdx.x;
    if (t < C0 * 18 * 9) {
        int c = t / 162, r = t % 162, o = r / 9, tap = r % 9;
        wofft[t] = w_off[(o * C0 + c) * 9 + tap];
    }
    if (t < 2 * 9 * C0 * C0) {
        int d = t / (9 * C0 * C0), r = t % (9 * C0 * C0);
        int k = r / (C0 * C0), r2 = r % (C0 * C0), o = r2 / C0, c = r2 % C0;
        const float* wsrc = d ? wd2 : wd1;
        float wv = wsrc[(o * C0 + c) * 9 + k];
        _Float16 hi = (_Float16)wv;
        float rr = wv - (float)hi;
        wdhi[t] = __builtin_bit_cast(u16, hi);
        wdlo[t] = f2h(rr);
    }
    if (t < 4 * C0 * C1) {
        int m = t / (C0 * C1), i = t % (C0 * C1);
        const float* s = (m == 0) ? s1c0 : (m == 1) ? s1h0 : (m == 2) ? s2c0 : s2h0;
        w0h[t] = f2h(s[i]);
    }
    if (t < 4 * C0 * C0) {
        int m = t / (C0 * C0), i = t % (C0 * C0);
        const float* s = (m == 0) ? s1c1 : (m == 1) ? s1h1 : (m == 2) ? s2c1 : s2h1;
        w1h[t] = f2h(s[i]);
    }
}

// ---------------------------------------------------------------------------
// Offset conv: 3x3, 128 -> 18 (f32, round-1 proven)
__global__ __launch_bounds__(256) void k_conv_off(
    const float* __restrict__ x0, const float* __restrict__ wofft,
    const float* __restrict__ boff, float* __restrict__ off)
{
    int bx = blockIdx.x;
    int b  = bx / TPB;
    int p0 = (bx % TPB) * PT;
    int tid = threadIdx.x;
    int p   = tid & 63;
    int cq  = __builtin_amdgcn_readfirstlane(tid >> 6);
    int pos = p0 + p;
    int h = pos / W_, w = pos % W_;

    float acc[18];
#pragma unroll
    for (int o = 0; o < 18; ++o) acc[o] = 0.f;

    for (int cc = 0; cc < 32; ++cc) {
        int c = cq * 32 + cc;
        const float* xb = x0 + ((size_t)(b * C0 + c)) * HW;
        float v[9];
#pragma unroll
        for (int t = 0; t < 9; ++t) {
            int dy = t / 3 - 1, dx = t % 3 - 1;
            int hy = h + dy, wx = w + dx;
            bool ok = (hy >= 0) & (hy < H_) & (wx >= 0) & (wx < W_);
            v[t] = ok ? xb[hy * W_ + wx] : 0.f;
        }
        const float* wr = wofft + c * 162;
#pragma unroll
        for (int o = 0; o < 18; ++o)
#pragma unroll
            for (int t = 0; t < 9; ++t)
                acc[o] = fmaf(wr[o * 9 + t], v[t], acc[o]);
    }

    __shared__ float red[4][18][PT];
#pragma unroll
    for (int o = 0; o < 18; ++o) red[cq][o][p] = acc[o];
    __syncthreads();
    for (int idx = tid; idx < 18 * PT; idx += 256) {
        int o = idx / PT, pp = idx % PT;
        float s = red[0][o][pp] + red[1][o][pp] + red[2][o][pp] + red[3][o][pp]
                + boff[o];
        off[((size_t)(b * 18 + o)) * HW + p0 + pp] = s;
    }
}

// ---------------------------------------------------------------------------
// Fused SFT via MFMA (unchanged from round 8; proven absmax 0.0156)
template <int XSRC>
__global__ __launch_bounds__(512) void k_sft_mma(
    const float* __restrict__ xf,     // XSRC==0
    const float* __restrict__ xT,     // XSRC==1
    const float* __restrict__ x1,
    const u16* __restrict__ w0s, const u16* __restrict__ w0h,   // [128 hid][32 ch]
    const u16* __restrict__ w1s, const u16* __restrict__ w1h,   // [128 out][128 hid]
    const float* __restrict__ b0s, const float* __restrict__ b0h,
    const float* __restrict__ b1s, const float* __restrict__ b1h,
    float* __restrict__ outT)         // [B,HW,128]
{
    __shared__ __align__(16) u16   x1t[64 * 32];
    __shared__ __align__(16) u16   hidt[2][64 * 128];
    __shared__ __align__(16) float outt[64 * 128];

    int bx = blockIdx.x, b = bx / TPB, p0 = (bx % TPB) * PT;
    int tid = threadIdx.x, l = tid & 63;
    int w = __builtin_amdgcn_readfirstlane(tid >> 6);
    f32x4 zz = {0.f, 0.f, 0.f, 0.f};

    for (int i = tid; i < C1 * PT; i += 512) {
        int ch = i >> 6, pos = i & 63;
        float v = x1[((size_t)(b * C1 + ch)) * HW + p0 + pos];
        x1t[pos * 32 + (ch ^ ((pos & 3) << 3))] = f2h(v);
    }
    __syncthreads();

    {   // hidden GEMM (K=32)
        int mt = w & 3, br = w >> 2;
        int pos = mt * 16 + (l & 15);
        int koff = (l >> 4) * 8;
        f16x8 a = *(const f16x8*)&x1t[pos * 32 + (koff ^ ((pos & 3) << 3))];
        const u16* w0 = br ? w0h : w0s;
        const float* bb = br ? b0h : b0s;
        u16* hrow = hidt[br];
#pragma unroll
        for (int nt = 0; nt < 8; ++nt) {
            int n = nt * 16 + (l & 15);
            f16x8 bfr = *(const f16x8*)&w0[n * 32 + koff];
            f32x4 h = __builtin_amdgcn_mfma_f32_16x16x32_f16(a, bfr, zz, 0, 0, 0);
            float bv = bb[n];
#pragma unroll
            for (int r = 0; r < 4; ++r) {
                float hv = h[r] + bv;
                hv = hv > 0.f ? hv : 0.1f * hv;
                int prow = mt * 16 + (l >> 4) * 4 + r;
                hrow[prow * 128 + (n ^ ((prow & 7) << 3))] = f2h(hv);
            }
        }
    }
    __syncthreads();

    f32x4 accS[4], accH[4];
#pragma unroll
    for (int nt = 0; nt < 4; ++nt) { accS[nt] = zz; accH[nt] = zz; }
    int mt = w & 3, nh = w >> 2;
    int pos = mt * 16 + (l & 15);
#pragma unroll
    for (int ks = 0; ks < 4; ++ks) {
        int kb = ks * 32 + (l >> 4) * 8;
        f16x8 aS = *(const f16x8*)&hidt[0][pos * 128 + (kb ^ ((pos & 7) << 3))];
        f16x8 aH = *(const f16x8*)&hidt[1][pos * 128 + (kb ^ ((pos & 7) << 3))];
#pragma unroll
        for (int nt = 0; nt < 4; ++nt) {
            int n = nh * 64 + nt * 16 + (l & 15);
            f16x8 bS = *(const f16x8*)&w1s[n * 128 + kb];
            f16x8 bH = *(const f16x8*)&w1h[n * 128 + kb];
            accS[nt] = __builtin_amdgcn_mfma_f32_16x16x32_f16(aS, bS, accS[nt], 0, 0, 0);
            accH[nt] = __builtin_amdgcn_mfma_f32_16x16x32_f16(aH, bH, accH[nt], 0, 0, 0);
        }
    }

#pragma unroll
    for (int nt = 0; nt < 4; ++nt) {
        int n = nh * 64 + nt * 16 + (l & 15);
        float scb = b1s[n], shb = b1h[n];
        float xv[4];
        if (XSRC == 0) {
            const float* xp = xf + ((size_t)(b * C0 + n)) * HW + p0 + mt * 16 + (l >> 4) * 4;
            f32x4 x4 = *(const f32x4*)xp;
#pragma unroll
            for (int r = 0; r < 4; ++r) xv[r] = x4[r];
        } else {
#pragma unroll
            for (int r = 0; r < 4; ++r)
                xv[r] = xT[((size_t)(b * HW + p0 + mt * 16 + (l >> 4) * 4 + r)) * C0 + n];
        }
#pragma unroll
        for (int r = 0; r < 4; ++r) {
            float scale = accS[nt][r] + scb + 1.f;
            float shift = accH[nt][r] + shb;
            outt[(mt * 16 + (l >> 4) * 4 + r) * 128 + n] = xv[r] * scale + shift;
        }
    }
    __syncthreads();

    float* dst = outT + ((size_t)(b * HW + p0)) * C0;
    for (int i = tid; i < 2048; i += 512)
        *(f32x4*)&dst[i * 4] = *(const f32x4*)&outt[i * 4];
}

// ---------------------------------------------------------------------------
// Deformable conv 3x3, split-f16 3-term MFMA, v2:
//  - all-tap coords precomputed in LDS (validity packed in idx bit 15)
//  - corner loads for tap k+1 issued before tap k's MFMA (latency hiding)
//  - padded LDS stride (136 u16 = 272 B) for uniform bank access
// MODE 0: ReLU -> f32 [B,HW,128].  MODE 1: + bias + x0 -> f32 [B,128,HW].
template <int MODE>
__global__ __launch_bounds__(512, 4) void k_deform4(
    const float* __restrict__ srcT,  // [B,HW,128] f32
    const float* __restrict__ off,   // [B,18,HW]
    const u16* __restrict__ whi,     // [9][128 o][128 c] f16 hi
    const u16* __restrict__ wlo,     // [9][128 o][128 c] f16 lo
    const float* __restrict__ bias,
    const float* __restrict__ x0,
    float* __restrict__ outF,        // MODE 1
    float* __restrict__ outT)        // MODE 0
{
    constexpr int S = 136;                            // padded u16 stride
    __shared__ __align__(16) u16   smem[4 * 64 * S];  // 69632 B
    __shared__ __align__(16) u16   cidx[9 * 64 * 4];  // 4608 B
    __shared__ __align__(16) float cwt[9 * 64 * 2];   // 4608 B
    u16* a_hi = smem;
    u16* a_lo = smem + 64 * S;
    u16* b_hi = smem + 2 * 64 * S;
    u16* b_lo = smem + 3 * 64 * S;

    int bx = blockIdx.x;
    bx = (bx & 7) * (NTILE / 8) + (bx >> 3);          // XCD swizzle
    int b = bx / TPB, p0 = (bx % TPB) * PT;
    int tid = threadIdx.x, l = tid & 63;
    int w = __builtin_amdgcn_readfirstlane(tid >> 6);
    f32x4 zz = {0.f, 0.f, 0.f, 0.f};

    // Phase 0: coords for all 9 taps (computed once)
    for (int e = tid; e < 9 * 64; e += 512) {
        int k = e >> 6, pp = e & 63;
        int pos = p0 + pp, h = pos / W_, wc = pos % W_;
        float dy = off[((size_t)(b * 18 + 2 * k)) * HW + pos];
        float dx = off[((size_t)(b * 18 + 2 * k + 1)) * HW + pos];
        float py = dy + (float)(h + k / 3 - 1);
        float px = dx + (float)(wc + k % 3 - 1);
        float yf = floorf(py), xf = floorf(px);
        int y0 = (int)yf, x0i = (int)xf;
        cwt[e * 2]     = py - yf;
        cwt[e * 2 + 1] = px - xf;
        int iy0 = min(max(y0, 0), H_ - 1),     iy1 = min(max(y0 + 1, 0), H_ - 1);
        int ix0 = min(max(x0i, 0), W_ - 1),    ix1 = min(max(x0i + 1, 0), W_ - 1);
        bool vy0 = (y0 >= 0) & (y0 < H_),      vy1 = (y0 + 1 >= 0) & (y0 + 1 < H_);
        bool vx0 = (x0i >= 0) & (x0i < W_),    vx1 = (x0i + 1 >= 0) & (x0i + 1 < W_);
        cidx[e * 4 + 0] = (u16)(iy0 * W_ + ix0) | ((vy0 & vx0) ? 0x8000 : 0);
        cidx[e * 4 + 1] = (u16)(iy0 * W_ + ix1) | ((vy0 & vx1) ? 0x8000 : 0);
        cidx[e * 4 + 2] = (u16)(iy1 * W_ + ix0) | ((vy1 & vx0) ? 0x8000 : 0);
        cidx[e * 4 + 3] = (u16)(iy1 * W_ + ix1) | ((vy1 & vx1) ? 0x8000 : 0);
    }
    __syncthreads();

    f32x4 acc[2][2];
#pragma unroll
    for (int hf = 0; hf < 2; ++hf)
#pragma unroll
        for (int nt = 0; nt < 2; ++nt) acc[hf][nt] = zz;

    int mt = w & 3, ng = w >> 2;          // 4 m-tiles x 2 n-groups
    int pos_r = mt * 16 + (l & 15);
    int so = tid >> 3, sp = tid & 7;      // B staging mapping
    const float* base  = srcT + (size_t)b * HW * C0;
    const float* lbase = base + 2 * l;    // per-lane channel pair

    f32x2 gv[8][4];                       // in-flight corner loads (64 VGPR)

#define ISSUE(KK)                                                             \
    {                                                                         \
        int ek = (KK) * 64 + w * 8;                                           \
        _Pragma("unroll")                                                     \
        for (int i = 0; i < 8; ++i) {                                         \
            int e = ek + i;                                                   \
            u32 c01 = *(const u32*)&cidx[e * 4];                              \
            u32 c23 = *(const u32*)&cidx[e * 4 + 2];                          \
            gv[i][0] = *(const f32x2*)(lbase + (size_t)(c01 & 0x3fffu) * C0); \
            gv[i][1] = *(const f32x2*)(lbase + (size_t)((c01 >> 16) & 0x3fffu) * C0); \
            gv[i][2] = *(const f32x2*)(lbase + (size_t)(c23 & 0x3fffu) * C0); \
            gv[i][3] = *(const f32x2*)(lbase + (size_t)((c23 >> 16) & 0x3fffu) * C0); \
        }                                                                     \
    }

#define COMMIT(KK)                                                            \
    {                                                                         \
        int ek = (KK) * 64 + w * 8;                                           \
        _Pragma("unroll")                                                     \
        for (int i = 0; i < 8; ++i) {                                         \
            int e = ek + i, pp = w * 8 + i;                                   \
            u32 c01 = *(const u32*)&cidx[e * 4];                              \
            u32 c23 = *(const u32*)&cidx[e * 4 + 2];                          \
            float wy = cwt[e * 2], wx = cwt[e * 2 + 1];                       \
            float aa  = wy * wx;                                              \
            float w11 = (c23 & 0x80000000u) ? aa : 0.f;                       \
            float w10 = (c23 & 0x8000u) ? (wy - aa) : 0.f;                    \
            float w01 = (c01 & 0x80000000u) ? (wx - aa) : 0.f;                \
            float w00 = (c01 & 0x8000u) ? (1.f - wy - wx + aa) : 0.f;         \
            float s0 = gv[i][0][0] * w00 + gv[i][1][0] * w01                  \
                     + gv[i][2][0] * w10 + gv[i][3][0] * w11;                 \
            float s1 = gv[i][0][1] * w00 + gv[i][1][1] * w01                  \
                     + gv[i][2][1] * w10 + gv[i][3][1] * w11;                 \
            _Float16 h0 = (_Float16)s0, h1 = (_Float16)s1;                    \
            float r0 = s0 - (float)h0, r1 = s1 - (float)h1;                   \
            u32 hv = (u32)__builtin_bit_cast(u16, h0)                         \
                   | ((u32)__builtin_bit_cast(u16, h1) << 16);                \
            u32 lv = (u32)f2h(r0) | ((u32)f2h(r1) << 16);                     \
            *(u32*)&a_hi[pp * S + 2 * l] = hv;                                \
            *(u32*)&a_lo[pp * S + 2 * l] = lv;                                \
        }                                                                     \
    }

#define STAGEB(KK, HF)                                                        \
    {                                                                         \
        int orow = (HF) * 64 + so;                                            \
        const u16* sh = whi + ((size_t)(KK) * C0 + orow) * C0 + sp * 16;      \
        const u16* sl = wlo + ((size_t)(KK) * C0 + orow) * C0 + sp * 16;      \
        _Pragma("unroll")                                                     \
        for (int j = 0; j < 2; ++j) {                                         \
            *(u32x4*)&b_hi[so * S + sp * 16 + j * 8] = *(const u32x4*)&sh[j * 8]; \
            *(u32x4*)&b_lo[so * S + sp * 16 + j * 8] = *(const u32x4*)&sl[j * 8]; \
        }                                                                     \
    }

#define MFMA_HALF(HF)                                                         \
    {                                                                         \
        _Pragma("unroll")                                                     \
        for (int ks = 0; ks < 4; ++ks) {                                      \
            int kb = ks * 32 + (l >> 4) * 8;                                  \
            int ai = pos_r * S + kb;                                          \
            f16x8 ah = *(const f16x8*)&a_hi[ai];                              \
            f16x8 al = *(const f16x8*)&a_lo[ai];                              \
            _Pragma("unroll")                                                 \
            for (int nt = 0; nt < 2; ++nt) {                                  \
                int orow = ng * 32 + nt * 16 + (l & 15);                      \
                int bi = orow * S + kb;                                       \
                f16x8 bh = *(const f16x8*)&b_hi[bi];                          \
                f16x8 bl = *(const f16x8*)&b_lo[bi];                          \
                acc[HF][nt] = __builtin_amdgcn_mfma_f32_16x16x32_f16(ah, bh, acc[HF][nt], 0, 0, 0); \
                acc[HF][nt] = __builtin_amdgcn_mfma_f32_16x16x32_f16(al, bh, acc[HF][nt], 0, 0, 0); \
                acc[HF][nt] = __builtin_amdgcn_mfma_f32_16x16x32_f16(ah, bl, acc[HF][nt], 0, 0, 0); \
            }                                                                 \
        }                                                                     \
    }

    ISSUE(0)
    for (int k = 0; k < 9; ++k) {
        COMMIT(k)
        STAGEB(k, 0)
        __syncthreads();
        if (k < 8) ISSUE(k + 1)           // in flight during both MFMA halves
        MFMA_HALF(0)
        __syncthreads();
        STAGEB(k, 1)
        __syncthreads();
        MFMA_HALF(1)
        __syncthreads();
    }
#undef ISSUE
#undef COMMIT
#undef STAGEB
#undef MFMA_HALF

    if (MODE == 0) {
        float* otile = (float*)smem;      // [64][132] f32, padded
#pragma unroll
        for (int hf = 0; hf < 2; ++hf)
#pragma unroll
            for (int nt = 0; nt < 2; ++nt) {
                int o = hf * 64 + ng * 32 + nt * 16 + (l & 15);
                float bv = bias[o];
#pragma unroll
                for (int r = 0; r < 4; ++r) {
                    float v = acc[hf][nt][r] + bv;
                    v = v > 0.f ? v : 0.f;
                    otile[(mt * 16 + (l >> 4) * 4 + r) * 132 + o] = v;
                }
            }
        __syncthreads();
        float* dst = outT + ((size_t)(b * HW + p0)) * C0;
        for (int i = tid; i < 2048; i += 512) {
            int row = i >> 5, c = i & 31;
            *(f32x4*)&dst[row * 128 + c * 4] = *(const f32x4*)&otile[row * 132 + c * 4];
        }
    } else {
#pragma unroll
        for (int hf = 0; hf < 2; ++hf)
#pragma unroll
            for (int nt = 0; nt < 2; ++nt) {
                int o = hf * 64 + ng * 32 + nt * 16 + (l & 15);
                float bv = bias[o];
                size_t base_o = ((size_t)(b * C0 + o)) * HW + p0 + mt * 16 + (l >> 4) * 4;
                f32x4 x4 = *(const f32x4*)(x0 + base_o);
                f32x4 ov;
#pragma unroll
                for (int r = 0; r < 4; ++r) ov[r] = acc[hf][nt][r] + bv + x4[r];
                *(f32x4*)(outF + base_o) = ov;
            }
    }
}

// ---------------------------------------------------------------------------
// Workspace layout (bytes)
constexpr size_t WB_OFF   = 0;            // f32 [B,18,HW]        2,654,208
constexpr size_t WB_WOFFT = 2654208;      // f32 [128][162]          82,944
constexpr size_t WB_W0H   = 2737152;      // f16 [4][128][32]        32,768
constexpr size_t WB_W1H   = 2769920;      // f16 [4][128][128]      131,072
constexpr size_t WB_WDHI  = 2900992;      // f16 [2][9][128][128] 1,179,648
constexpr size_t WB_WDLO  = 4080640;      // f16 [2][9][128][128] 1,179,648
constexpr size_t WB_TA    = 5260288;      // f32 [B,HW,128]      18,874,368
constexpr size_t WB_TB    = 24134656;     // f32 [B,HW,128]      18,874,368
// total 43,009,024 B

extern "C" void kernel_launch(void* const* d_in, const int* in_sizes, int n_in,
                              void* d_out, int out_size, void* d_ws, size_t ws_size,
                              hipStream_t stream)
{
    const float* x0      = (const float*)d_in[0];
    const float* x1      = (const float*)d_in[1];
    const float* w_off   = (const float*)d_in[2];
    const float* b_off   = (const float*)d_in[3];
    const float* s1_sc0w = (const float*)d_in[4];
    const float* s1_sc0b = (const float*)d_in[5];
    const float* s1_sc1w = (const float*)d_in[6];
    const float* s1_sc1b = (const float*)d_in[7];
    const float* s1_sh0w = (const float*)d_in[8];
    const float* s1_sh0b = (const float*)d_in[9];
    const float* s1_sh1w = (const float*)d_in[10];
    const float* s1_sh1b = (const float*)d_in[11];
    const float* w_d1    = (const float*)d_in[12];
    const float* b_d1    = (const float*)d_in[13];
    const float* s2_sc0w = (const float*)d_in[14];
    const float* s2_sc0b = (const float*)d_in[15];
    const float* s2_sc1w = (const float*)d_in[16];
    const float* s2_sc1b = (const float*)d_in[17];
    const float* s2_sh0w = (const float*)d_in[18];
    const float* s2_sh0b = (const float*)d_in[19];
    const float* s2_sh1w = (const float*)d_in[20];
    const float* s2_sh1b = (const float*)d_in[21];
    const float* w_d2    = (const float*)d_in[22];
    const float* b_d2    = (const float*)d_in[23];

    char* wsb = (char*)d_ws;
    float* off   = (float*)(wsb + WB_OFF);
    float* wofft = (float*)(wsb + WB_WOFFT);
    u16*   w0h   = (u16*)(wsb + WB_W0H);
    u16*   w1h   = (u16*)(wsb + WB_W1H);
    u16*   wdhi  = (u16*)(wsb + WB_WDHI);
    u16*   wdlo  = (u16*)(wsb + WB_WDLO);
    float* TA    = (float*)(wsb + WB_TA);
    float* TB    = (float*)(wsb + WB_TB);

    k_prep<<<1152, 256, 0, stream>>>(w_off, w_d1, w_d2,
                                     s1_sc0w, s1_sh0w, s2_sc0w, s2_sh0w,
                                     s1_sc1w, s1_sh1w, s2_sc1w, s2_sh1w,
                                     wofft, wdhi, wdlo, w0h, w1h);
    k_conv_off<<<NTILE, 256, 0, stream>>>(x0, wofft, b_off, off);
    // SFT1: x = x0 (channel-major) -> TA (position-major)
    k_sft_mma<0><<<NTILE, 512, 0, stream>>>(x0, nullptr, x1,
                                            w0h, w0h + 4096,
                                            w1h, w1h + 16384,
                                            s1_sc0b, s1_sh0b, s1_sc1b, s1_sh1b, TA);
    // dconv1: gather TA -> relu -> TB (position-major)
    k_deform4<0><<<NTILE, 512, 0, stream>>>(TA, off, wdhi, wdlo, b_d1,
                                            nullptr, nullptr, TB);
    // SFT2: x = TB (position-major) -> TA (position-major)
    k_sft_mma<1><<<NTILE, 512, 0, stream>>>(nullptr, TB, x1,
                                            w0h + 8192, w0h + 12288,
                                            w1h + 32768, w1h + 49152,
                                            s2_sc0b, s2_sh0b, s2_sc1b, s2_sh1b, TA);
    // dconv2: gather TA -> +bias +x0 -> d_out (channel-major)
    k_deform4<1><<<NTILE, 512, 0, stream>>>(TA, off, wdhi + 9 * 16384, wdlo + 9 * 16384,
                                            b_d2, x0, (float*)d_out, nullptr);
}

// Round 10
// 365.205 us; speedup vs baseline: 1.9016x; 1.0222x over previous
//
#include <hip/hip_runtime.h>

typedef unsigned short u16;
typedef unsigned int   u32;
typedef __attribute__((ext_vector_type(8))) _Float16 f16x8;
typedef __attribute__((ext_vector_type(2))) float f32x2;
typedef __attribute__((ext_vector_type(4))) float f32x4;
typedef __attribute__((ext_vector_type(4))) unsigned int u32x4;

constexpr int B_  = 4;
constexpr int C0  = 128;
constexpr int C1  = 32;
constexpr int H_  = 96;
constexpr int W_  = 96;
constexpr int HW  = H_ * W_;        // 9216
constexpr int PT  = 64;
constexpr int TPB = HW / PT;        // 144
constexpr int NTILE = B_ * TPB;     // 576

__device__ inline u16 f2h(float f) {
    _Float16 h = (_Float16)f;
    return __builtin_bit_cast(u16, h);
}

// ---------------------------------------------------------------------------
// Weight prep (unchanged)
__global__ __launch_bounds__(256) void k_prep(
    const float* __restrict__ w_off,
    const float* __restrict__ wd1,  const float* __restrict__ wd2,
    const float* __restrict__ s1c0, const float* __restrict__ s1h0,
    const float* __restrict__ s2c0, const float* __restrict__ s2h0,
    const float* __restrict__ s1c1, const float* __restrict__ s1h1,
    const float* __restrict__ s2c1, const float* __restrict__ s2h1,
    float* __restrict__ wofft, u16* __restrict__ wdhi, u16* __restrict__ wdlo,
    u16* __restrict__ w0h,     u16* __restrict__ w1h)
{
    int t = blockIdx.x * 256 + threadIdx.x;
    if (t < C0 * 18 * 9) {
        int c = t / 162, r = t % 162, o = r / 9, tap = r % 9;
        wofft[t] = w_off[(o * C0 + c) * 9 + tap];
    }
    if (t < 2 * 9 * C0 * C0) {
        int d = t / (9 * C0 * C0), r = t % (9 * C0 * C0);
        int k = r / (C0 * C0), r2 = r % (C0 * C0), o = r2 / C0, c = r2 % C0;
        const float* wsrc = d ? wd2 : wd1;
        float wv = wsrc[(o * C0 + c) * 9 + k];
        _Float16 hi = (_Float16)wv;
        float rr = wv - (float)hi;
        wdhi[t] = __builtin_bit_cast(u16, hi);
        wdlo[t] = f2h(rr);
    }
    if (t < 4 * C0 * C1) {
        int m = t / (C0 * C1), i = t % (C0 * C1);
        const float* s = (m == 0) ? s1c0 : (m == 1) ? s1h0 : (m == 2) ? s2c0 : s2h0;
        w0h[t] = f2h(s[i]);
    }
    if (t < 4 * C0 * C0) {
        int m = t / (C0 * C0), i = t % (C0 * C0);
        const float* s = (m == 0) ? s1c1 : (m == 1) ? s1h1 : (m == 2) ? s2c1 : s2h1;
        w1h[t] = f2h(s[i]);
    }
}

// ---------------------------------------------------------------------------
// Offset conv: 3x3, 128 -> 18 (f32, round-1 proven)
__global__ __launch_bounds__(256) void k_conv_off(
    const float* __restrict__ x0, const float* __restrict__ wofft,
    const float* __restrict__ boff, float* __restrict__ off)
{
    int bx = blockIdx.x;
    int b  = bx / TPB;
    int p0 = (bx % TPB) * PT;
    int tid = threadIdx.x;
    int p   = tid & 63;
    int cq  = __builtin_amdgcn_readfirstlane(tid >> 6);
    int pos = p0 + p;
    int h = pos / W_, w = pos % W_;

    float acc[18];
#pragma unroll
    for (int o = 0; o < 18; ++o) acc[o] = 0.f;

    for (int cc = 0; cc < 32; ++cc) {
        int c = cq * 32 + cc;
        const float* xb = x0 + ((size_t)(b * C0 + c)) * HW;
        float v[9];
#pragma unroll
        for (int t = 0; t < 9; ++t) {
            int dy = t / 3 - 1, dx = t % 3 - 1;
            int hy = h + dy, wx = w + dx;
            bool ok = (hy >= 0) & (hy < H_) & (wx >= 0) & (wx < W_);
            v[t] = ok ? xb[hy * W_ + wx] : 0.f;
        }
        const float* wr = wofft + c * 162;
#pragma unroll
        for (int o = 0; o < 18; ++o)
#pragma unroll
            for (int t = 0; t < 9; ++t)
                acc[o] = fmaf(wr[o * 9 + t], v[t], acc[o]);
    }

    __shared__ float red[4][18][PT];
#pragma unroll
    for (int o = 0; o < 18; ++o) red[cq][o][p] = acc[o];
    __syncthreads();
    for (int idx = tid; idx < 18 * PT; idx += 256) {
        int o = idx / PT, pp = idx % PT;
        float s = red[0][o][pp] + red[1][o][pp] + red[2][o][pp] + red[3][o][pp]
                + boff[o];
        off[((size_t)(b * 18 + o)) * HW + p0 + pp] = s;
    }
}

// ---------------------------------------------------------------------------
// Fused SFT via MFMA (unchanged; proven absmax 0.0156)
template <int XSRC>
__global__ __launch_bounds__(512) void k_sft_mma(
    const float* __restrict__ xf,     // XSRC==0
    const float* __restrict__ xT,     // XSRC==1
    const float* __restrict__ x1,
    const u16* __restrict__ w0s, const u16* __restrict__ w0h,   // [128 hid][32 ch]
    const u16* __restrict__ w1s, const u16* __restrict__ w1h,   // [128 out][128 hid]
    const float* __restrict__ b0s, const float* __restrict__ b0h,
    const float* __restrict__ b1s, const float* __restrict__ b1h,
    float* __restrict__ outT)         // [B,HW,128]
{
    __shared__ __align__(16) u16   x1t[64 * 32];
    __shared__ __align__(16) u16   hidt[2][64 * 128];
    __shared__ __align__(16) float outt[64 * 128];

    int bx = blockIdx.x, b = bx / TPB, p0 = (bx % TPB) * PT;
    int tid = threadIdx.x, l = tid & 63;
    int w = __builtin_amdgcn_readfirstlane(tid >> 6);
    f32x4 zz = {0.f, 0.f, 0.f, 0.f};

    for (int i = tid; i < C1 * PT; i += 512) {
        int ch = i >> 6, pos = i & 63;
        float v = x1[((size_t)(b * C1 + ch)) * HW + p0 + pos];
        x1t[pos * 32 + (ch ^ ((pos & 3) << 3))] = f2h(v);
    }
    __syncthreads();

    {   // hidden GEMM (K=32)
        int mt = w & 3, br = w >> 2;
        int pos = mt * 16 + (l & 15);
        int koff = (l >> 4) * 8;
        f16x8 a = *(const f16x8*)&x1t[pos * 32 + (koff ^ ((pos & 3) << 3))];
        const u16* w0 = br ? w0h : w0s;
        const float* bb = br ? b0h : b0s;
        u16* hrow = hidt[br];
#pragma unroll
        for (int nt = 0; nt < 8; ++nt) {
            int n = nt * 16 + (l & 15);
            f16x8 bfr = *(const f16x8*)&w0[n * 32 + koff];
            f32x4 h = __builtin_amdgcn_mfma_f32_16x16x32_f16(a, bfr, zz, 0, 0, 0);
            float bv = bb[n];
#pragma unroll
            for (int r = 0; r < 4; ++r) {
                float hv = h[r] + bv;
                hv = hv > 0.f ? hv : 0.1f * hv;
                int prow = mt * 16 + (l >> 4) * 4 + r;
                hrow[prow * 128 + (n ^ ((prow & 7) << 3))] = f2h(hv);
            }
        }
    }
    __syncthreads();

    f32x4 accS[4], accH[4];
#pragma unroll
    for (int nt = 0; nt < 4; ++nt) { accS[nt] = zz; accH[nt] = zz; }
    int mt = w & 3, nh = w >> 2;
    int pos = mt * 16 + (l & 15);
#pragma unroll
    for (int ks = 0; ks < 4; ++ks) {
        int kb = ks * 32 + (l >> 4) * 8;
        f16x8 aS = *(const f16x8*)&hidt[0][pos * 128 + (kb ^ ((pos & 7) << 3))];
        f16x8 aH = *(const f16x8*)&hidt[1][pos * 128 + (kb ^ ((pos & 7) << 3))];
#pragma unroll
        for (int nt = 0; nt < 4; ++nt) {
            int n = nh * 64 + nt * 16 + (l & 15);
            f16x8 bS = *(const f16x8*)&w1s[n * 128 + kb];
            f16x8 bH = *(const f16x8*)&w1h[n * 128 + kb];
            accS[nt] = __builtin_amdgcn_mfma_f32_16x16x32_f16(aS, bS, accS[nt], 0, 0, 0);
            accH[nt] = __builtin_amdgcn_mfma_f32_16x16x32_f16(aH, bH, accH[nt], 0, 0, 0);
        }
    }

#pragma unroll
    for (int nt = 0; nt < 4; ++nt) {
        int n = nh * 64 + nt * 16 + (l & 15);
        float scb = b1s[n], shb = b1h[n];
        float xv[4];
        if (XSRC == 0) {
            const float* xp = xf + ((size_t)(b * C0 + n)) * HW + p0 + mt * 16 + (l >> 4) * 4;
            f32x4 x4 = *(const f32x4*)xp;
#pragma unroll
            for (int r = 0; r < 4; ++r) xv[r] = x4[r];
        } else {
#pragma unroll
            for (int r = 0; r < 4; ++r)
                xv[r] = xT[((size_t)(b * HW + p0 + mt * 16 + (l >> 4) * 4 + r)) * C0 + n];
        }
#pragma unroll
        for (int r = 0; r < 4; ++r) {
            float scale = accS[nt][r] + scb + 1.f;
            float shift = accH[nt][r] + shb;
            outt[(mt * 16 + (l >> 4) * 4 + r) * 128 + n] = xv[r] * scale + shift;
        }
    }
    __syncthreads();

    float* dst = outT + ((size_t)(b * HW + p0)) * C0;
    for (int i = tid; i < 2048; i += 512)
        *(f32x4*)&dst[i * 4] = *(const f32x4*)&outt[i * 4];
}

// ---------------------------------------------------------------------------
// Deformable conv 3x3, split-f16 3-term MFMA, v3: register-pipelined.
//  - A-gather corners issued in 4-position chunks one tap ahead (gv1/gv2)
//  - B weights global->reg one half ahead, ds_write just before publish
//  - MFMA phases contain no loads; sched_barrier pins issue points
// MODE 0: ReLU -> f32 [B,HW,128].  MODE 1: + bias + x0 -> f32 [B,128,HW].
template <int MODE>
__global__ __launch_bounds__(512, 4) void k_deform5(
    const float* __restrict__ srcT,  // [B,HW,128] f32
    const float* __restrict__ off,   // [B,18,HW]
    const u16* __restrict__ whi,     // [9][128 o][128 c] f16 hi
    const u16* __restrict__ wlo,     // [9][128 o][128 c] f16 lo
    const float* __restrict__ bias,
    const float* __restrict__ x0,
    float* __restrict__ outF,        // MODE 1
    float* __restrict__ outT)        // MODE 0
{
    constexpr int S = 136;                            // padded u16 stride
    __shared__ __align__(16) u16   smem[4 * 64 * S];  // 69632 B
    __shared__ __align__(16) u16   cidx[9 * 64 * 4];  // 4608 B
    __shared__ __align__(16) float cwt[9 * 64 * 2];   // 4608 B
    u16* a_hi = smem;
    u16* a_lo = smem + 64 * S;
    u16* b_hi = smem + 2 * 64 * S;
    u16* b_lo = smem + 3 * 64 * S;

    int bx = blockIdx.x;
    bx = (bx & 7) * (NTILE / 8) + (bx >> 3);          // XCD swizzle
    int b = bx / TPB, p0 = (bx % TPB) * PT;
    int tid = threadIdx.x, l = tid & 63;
    int w = __builtin_amdgcn_readfirstlane(tid >> 6);
    f32x4 zz = {0.f, 0.f, 0.f, 0.f};

    // Phase 0: coords for all 9 taps (computed once)
    for (int e = tid; e < 9 * 64; e += 512) {
        int k = e >> 6, pp = e & 63;
        int pos = p0 + pp, h = pos / W_, wc = pos % W_;
        float dy = off[((size_t)(b * 18 + 2 * k)) * HW + pos];
        float dx = off[((size_t)(b * 18 + 2 * k + 1)) * HW + pos];
        float py = dy + (float)(h + k / 3 - 1);
        float px = dx + (float)(wc + k % 3 - 1);
        float yf = floorf(py), xf = floorf(px);
        int y0 = (int)yf, x0i = (int)xf;
        cwt[e * 2]     = py - yf;
        cwt[e * 2 + 1] = px - xf;
        int iy0 = min(max(y0, 0), H_ - 1),     iy1 = min(max(y0 + 1, 0), H_ - 1);
        int ix0 = min(max(x0i, 0), W_ - 1),    ix1 = min(max(x0i + 1, 0), W_ - 1);
        bool vy0 = (y0 >= 0) & (y0 < H_),      vy1 = (y0 + 1 >= 0) & (y0 + 1 < H_);
        bool vx0 = (x0i >= 0) & (x0i < W_),    vx1 = (x0i + 1 >= 0) & (x0i + 1 < W_);
        cidx[e * 4 + 0] = (u16)(iy0 * W_ + ix0) | ((vy0 & vx0) ? 0x8000 : 0);
        cidx[e * 4 + 1] = (u16)(iy0 * W_ + ix1) | ((vy0 & vx1) ? 0x8000 : 0);
        cidx[e * 4 + 2] = (u16)(iy1 * W_ + ix0) | ((vy1 & vx0) ? 0x8000 : 0);
        cidx[e * 4 + 3] = (u16)(iy1 * W_ + ix1) | ((vy1 & vx1) ? 0x8000 : 0);
    }
    __syncthreads();

    f32x4 acc[2][2];
#pragma unroll
    for (int hf = 0; hf < 2; ++hf)
#pragma unroll
        for (int nt = 0; nt < 2; ++nt) acc[hf][nt] = zz;

    int mt = w & 3, ng = w >> 2;          // 4 m-tiles x 2 n-groups
    int pos_r = mt * 16 + (l & 15);
    int so = tid >> 3, sp = tid & 7;      // B staging mapping
    const float* base  = srcT + (size_t)b * HW * C0;
    const float* lbase = base + 2 * l;    // per-lane channel pair

    f32x2 gv1[4][4], gv2[4][4];           // in-flight A corners (32 VGPR)
    u32x4 rbh0, rbh1, rbl0, rbl1;         // in-flight B weights (16 VGPR)

#define ISSUE_A(DST, KK, IOFF)                                                \
    {                                                                         \
        int ek = (KK) * 64 + w * 8 + (IOFF);                                  \
        _Pragma("unroll")                                                     \
        for (int i = 0; i < 4; ++i) {                                         \
            int e = ek + i;                                                   \
            u32 c01 = *(const u32*)&cidx[e * 4];                              \
            u32 c23 = *(const u32*)&cidx[e * 4 + 2];                          \
            DST[i][0] = *(const f32x2*)(lbase + (size_t)(c01 & 0x3fffu) * C0);\
            DST[i][1] = *(const f32x2*)(lbase + (size_t)((c01 >> 16) & 0x3fffu) * C0); \
            DST[i][2] = *(const f32x2*)(lbase + (size_t)(c23 & 0x3fffu) * C0);\
            DST[i][3] = *(const f32x2*)(lbase + (size_t)((c23 >> 16) & 0x3fffu) * C0); \
        }                                                                     \
    }

#define COMMIT_HALF(SRC, KK, IOFF)                                            \
    {                                                                         \
        int ek = (KK) * 64 + w * 8 + (IOFF);                                  \
        _Pragma("unroll")                                                     \
        for (int i = 0; i < 4; ++i) {                                         \
            int e = ek + i, pp = w * 8 + (IOFF) + i;                          \
            u32 c01 = *(const u32*)&cidx[e * 4];                              \
            u32 c23 = *(const u32*)&cidx[e * 4 + 2];                          \
            float wy = cwt[e * 2], wx = cwt[e * 2 + 1];                       \
            float aa  = wy * wx;                                              \
            float w11 = (c23 & 0x80000000u) ? aa : 0.f;                       \
            float w10 = (c23 & 0x8000u) ? (wy - aa) : 0.f;                    \
            float w01 = (c01 & 0x80000000u) ? (wx - aa) : 0.f;                \
            float w00 = (c01 & 0x8000u) ? (1.f - wy - wx + aa) : 0.f;         \
            float s0 = SRC[i][0][0] * w00 + SRC[i][1][0] * w01                \
                     + SRC[i][2][0] * w10 + SRC[i][3][0] * w11;               \
            float s1 = SRC[i][0][1] * w00 + SRC[i][1][1] * w01                \
                     + SRC[i][2][1] * w10 + SRC[i][3][1] * w11;               \
            _Float16 h0 = (_Float16)s0, h1 = (_Float16)s1;                    \
            float r0 = s0 - (float)h0, r1 = s1 - (float)h1;                   \
            u32 hv = (u32)__builtin_bit_cast(u16, h0)                         \
                   | ((u32)__builtin_bit_cast(u16, h1) << 16);                \
            u32 lv = (u32)f2h(r0) | ((u32)f2h(r1) << 16);                     \
            *(u32*)&a_hi[pp * S + 2 * l] = hv;                                \
            *(u32*)&a_lo[pp * S + 2 * l] = lv;                                \
        }                                                                     \
    }

#define ISSUE_B(KK, HF)                                                       \
    {                                                                         \
        int orow = (HF) * 64 + so;                                            \
        const u16* sh = whi + ((size_t)(KK) * C0 + orow) * C0 + sp * 16;      \
        const u16* sl = wlo + ((size_t)(KK) * C0 + orow) * C0 + sp * 16;      \
        rbh0 = *(const u32x4*)&sh[0];  rbh1 = *(const u32x4*)&sh[8];          \
        rbl0 = *(const u32x4*)&sl[0];  rbl1 = *(const u32x4*)&sl[8];          \
    }

#define WRITE_B()                                                             \
    {                                                                         \
        *(u32x4*)&b_hi[so * S + sp * 16]     = rbh0;                          \
        *(u32x4*)&b_hi[so * S + sp * 16 + 8] = rbh1;                          \
        *(u32x4*)&b_lo[so * S + sp * 16]     = rbl0;                          \
        *(u32x4*)&b_lo[so * S + sp * 16 + 8] = rbl1;                          \
    }

#define MFMA_HALF(HF)                                                         \
    {                                                                         \
        _Pragma("unroll")                                                     \
        for (int ks = 0; ks < 4; ++ks) {                                      \
            int kb = ks * 32 + (l >> 4) * 8;                                  \
            int ai = pos_r * S + kb;                                          \
            f16x8 ah = *(const f16x8*)&a_hi[ai];                              \
            f16x8 al = *(const f16x8*)&a_lo[ai];                              \
            _Pragma("unroll")                                                 \
            for (int nt = 0; nt < 2; ++nt) {                                  \
                int orow = ng * 32 + nt * 16 + (l & 15);                      \
                int bi = orow * S + kb;                                       \
                f16x8 bh = *(const f16x8*)&b_hi[bi];                          \
                f16x8 bl = *(const f16x8*)&b_lo[bi];                          \
                acc[HF][nt] = __builtin_amdgcn_mfma_f32_16x16x32_f16(ah, bh, acc[HF][nt], 0, 0, 0); \
                acc[HF][nt] = __builtin_amdgcn_mfma_f32_16x16x32_f16(al, bh, acc[HF][nt], 0, 0, 0); \
                acc[HF][nt] = __builtin_amdgcn_mfma_f32_16x16x32_f16(ah, bl, acc[HF][nt], 0, 0, 0); \
            }                                                                 \
        }                                                                     \
    }

    // Prologue: fill the pipeline
    ISSUE_A(gv1, 0, 0)
    ISSUE_A(gv2, 0, 4)
    ISSUE_B(0, 0)

    for (int k = 0; k < 9; ++k) {
        // ---- half 0 ----
        COMMIT_HALF(gv1, k, 0)
        COMMIT_HALF(gv2, k, 4)
        WRITE_B()
        ISSUE_B(k, 1)                      // for half 1
        if (k < 8) ISSUE_A(gv1, k + 1, 0)  // for next tap
        __builtin_amdgcn_sched_barrier(0);
        __syncthreads();                   // publish A(k), B(k,0)
        MFMA_HALF(0)
        __syncthreads();                   // B half0 reads done
        // ---- half 1 ----
        WRITE_B()
        if (k < 8) { ISSUE_B(k + 1, 0) }   // for next tap half 0
        if (k < 8) { ISSUE_A(gv2, k + 1, 4) }
        __builtin_amdgcn_sched_barrier(0);
        __syncthreads();                   // publish B(k,1)
        MFMA_HALF(1)
        __syncthreads();                   // B half1 reads done (A rewritten next tap)
    }
#undef ISSUE_A
#undef COMMIT_HALF
#undef ISSUE_B
#undef WRITE_B
#undef MFMA_HALF

    if (MODE == 0) {
        float* otile = (float*)smem;      // [64][132] f32, padded
#pragma unroll
        for (int hf = 0; hf < 2; ++hf)
#pragma unroll
            for (int nt = 0; nt < 2; ++nt) {
                int o = hf * 64 + ng * 32 + nt * 16 + (l & 15);
                float bv = bias[o];
#pragma unroll
                for (int r = 0; r < 4; ++r) {
                    float v = acc[hf][nt][r] + bv;
                    v = v > 0.f ? v : 0.f;
                    otile[(mt * 16 + (l >> 4) * 4 + r) * 132 + o] = v;
                }
            }
        __syncthreads();
        float* dst = outT + ((size_t)(b * HW + p0)) * C0;
        for (int i = tid; i < 2048; i += 512) {
            int row = i >> 5, c = i & 31;
            *(f32x4*)&dst[row * 128 + c * 4] = *(const f32x4*)&otile[row * 132 + c * 4];
        }
    } else {
#pragma unroll
        for (int hf = 0; hf < 2; ++hf)
#pragma unroll
            for (int nt = 0; nt < 2; ++nt) {
                int o = hf * 64 + ng * 32 + nt * 16 + (l & 15);
                float bv = bias[o];
                size_t base_o = ((size_t)(b * C0 + o)) * HW + p0 + mt * 16 + (l >> 4) * 4;
                f32x4 x4 = *(const f32x4*)(x0 + base_o);
                f32x4 ov;
#pragma unroll
                for (int r = 0; r < 4; ++r) ov[r] = acc[hf][nt][r] + bv + x4[r];
                *(f32x4*)(outF + base_o) = ov;
            }
    }
}

// ---------------------------------------------------------------------------
// Workspace layout (bytes)
constexpr size_t WB_OFF   = 0;            // f32 [B,18,HW]        2,654,208
constexpr size_t WB_WOFFT = 2654208;      // f32 [128][162]          82,944
constexpr size_t WB_W0H   = 2737152;      // f16 [4][128][32]        32,768
constexpr size_t WB_W1H   = 2769920;      // f16 [4][128][128]      131,072
constexpr size_t WB_WDHI  = 2900992;      // f16 [2][9][128][128] 1,179,648
constexpr size_t WB_WDLO  = 4080640;      // f16 [2][9][128][128] 1,179,648
constexpr size_t WB_TA    = 5260288;      // f32 [B,HW,128]      18,874,368
constexpr size_t WB_TB    = 24134656;     // f32 [B,HW,128]      18,874,368
// total 43,009,024 B

extern "C" void kernel_launch(void* const* d_in, const int* in_sizes, int n_in,
                              void* d_out, int out_size, void* d_ws, size_t ws_size,
                              hipStream_t stream)
{
    const float* x0      = (const float*)d_in[0];
    const float* x1      = (const float*)d_in[1];
    const float* w_off   = (const float*)d_in[2];
    const float* b_off   = (const float*)d_in[3];
    const float* s1_sc0w = (const float*)d_in[4];
    const float* s1_sc0b = (const float*)d_in[5];
    const float* s1_sc1w = (const float*)d_in[6];
    const float* s1_sc1b = (const float*)d_in[7];
    const float* s1_sh0w = (const float*)d_in[8];
    const float* s1_sh0b = (const float*)d_in[9];
    const float* s1_sh1w = (const float*)d_in[10];
    const float* s1_sh1b = (const float*)d_in[11];
    const float* w_d1    = (const float*)d_in[12];
    const float* b_d1    = (const float*)d_in[13];
    const float* s2_sc0w = (const float*)d_in[14];
    const float* s2_sc0b = (const float*)d_in[15];
    const float* s2_sc1w = (const float*)d_in[16];
    const float* s2_sc1b = (const float*)d_in[17];
    const float* s2_sh0w = (const float*)d_in[18];
    const float* s2_sh0b = (const float*)d_in[19];
    const float* s2_sh1w = (const float*)d_in[20];
    const float* s2_sh1b = (const float*)d_in[21];
    const float* w_d2    = (const float*)d_in[22];
    const float* b_d2    = (const float*)d_in[23];

    char* wsb = (char*)d_ws;
    float* off   = (float*)(wsb + WB_OFF);
    float* wofft = (float*)(wsb + WB_WOFFT);
    u16*   w0h   = (u16*)(wsb + WB_W0H);
    u16*   w1h   = (u16*)(wsb + WB_W1H);
    u16*   wdhi  = (u16*)(wsb + WB_WDHI);
    u16*   wdlo  = (u16*)(wsb + WB_WDLO);
    float* TA    = (float*)(wsb + WB_TA);
    float* TB    = (float*)(wsb + WB_TB);

    k_prep<<<1152, 256, 0, stream>>>(w_off, w_d1, w_d2,
                                     s1_sc0w, s1_sh0w, s2_sc0w, s2_sh0w,
                                     s1_sc1w, s1_sh1w, s2_sc1w, s2_sh1w,
                                     wofft, wdhi, wdlo, w0h, w1h);
    k_conv_off<<<NTILE, 256, 0, stream>>>(x0, wofft, b_off, off);
    // SFT1: x = x0 (channel-major) -> TA (position-major)
    k_sft_mma<0><<<NTILE, 512, 0, stream>>>(x0, nullptr, x1,
                                            w0h, w0h + 4096,
                                            w1h, w1h + 16384,
                                            s1_sc0b, s1_sh0b, s1_sc1b, s1_sh1b, TA);
    // dconv1: gather TA -> relu -> TB (position-major)
    k_deform5<0><<<NTILE, 512, 0, stream>>>(TA, off, wdhi, wdlo, b_d1,
                                            nullptr, nullptr, TB);
    // SFT2: x = TB (position-major) -> TA (position-major)
    k_sft_mma<1><<<NTILE, 512, 0, stream>>>(nullptr, TB, x1,
                                            w0h + 8192, w0h + 12288,
                                            w1h + 32768, w1h + 49152,
                                            s2_sc0b, s2_sh0b, s2_sc1b, s2_sh1b, TA);
    // dconv2: gather TA -> +bias +x0 -> d_out (channel-major)
    k_deform5<1><<<NTILE, 512, 0, stream>>>(TA, off, wdhi + 9 * 16384, wdlo + 9 * 16384,
                                            b_d2, x0, (float*)d_out, nullptr);
}